// Round 7
// baseline (413.148 us; speedup 1.0000x reference)
//
#include <hip/hip_runtime.h>

#define N_NODES 100000
#define N_EDGES 1600000
#define D 128      // D_IN == D_HID
#define D_OUT 64
#define NXCD 8
#define NODES_PER_COLOR (N_NODES / NXCD)   // 12500 exactly
#define MAXDEG 64  // Poisson(16); max over 100k nodes ~35. 64 = safe pow2.

typedef __attribute__((ext_vector_type(8))) short short8;   // 8 bf16 (4 VGPRs)
typedef __attribute__((ext_vector_type(4))) float floatx4;  // MFMA C/D
typedef __attribute__((ext_vector_type(2))) float floatx2;

__device__ inline unsigned short f2bf(float f) {   // RNE f32 -> bf16
    unsigned u = __builtin_bit_cast(unsigned, f);
    u = (u + 0x7fffu + ((u >> 16) & 1u)) >> 16;
    return (unsigned short)u;
}
__device__ inline float bflo(unsigned v) { return __builtin_bit_cast(float, v << 16); }
__device__ inline float bfhi(unsigned v) { return __builtin_bit_cast(float, v & 0xffff0000u); }

// ---------------- f32 -> bf16 + fp8 bulk convert (8 elems/thread) ----------------
__global__ void to_bf16_fp8(const float* __restrict__ in, unsigned short* __restrict__ outb,
                            unsigned* __restrict__ out8, int n8) {
    int i = blockIdx.x * blockDim.x + threadIdx.x;
    if (i >= n8) return;
    const float4* p = (const float4*)in + 2 * (size_t)i;
    float4 a = p[0], b = p[1];
    uint4 u;
    u.x = (unsigned)f2bf(a.x) | ((unsigned)f2bf(a.y) << 16);
    u.y = (unsigned)f2bf(a.z) | ((unsigned)f2bf(a.w) << 16);
    u.z = (unsigned)f2bf(b.x) | ((unsigned)f2bf(b.y) << 16);
    u.w = (unsigned)f2bf(b.z) | ((unsigned)f2bf(b.w) << 16);
    ((uint4*)outb)[i] = u;
    int v0 = __builtin_amdgcn_cvt_pk_fp8_f32(a.x, a.y, 0, false);
    v0     = __builtin_amdgcn_cvt_pk_fp8_f32(a.z, a.w, v0, true);
    int v1 = __builtin_amdgcn_cvt_pk_fp8_f32(b.x, b.y, 0, false);
    v1     = __builtin_amdgcn_cvt_pk_fp8_f32(b.z, b.w, v1, true);
    uint2 w8; w8.x = (unsigned)v0; w8.y = (unsigned)v1;
    ((uint2*)out8)[i] = w8;
}

// ------- single-pass colored padded-CSR build (degree + fill, no scan) -------
// Non-temporal src/dst streams keep partially-filled csrp sectors resident in
// the owning XCD's L2 until they are dense -> minimal write amplification.
__global__ __launch_bounds__(256) void build_padded(
        const int* __restrict__ src, const int* __restrict__ dst,
        int* __restrict__ dcount, int* __restrict__ csrp) {
    const int color = blockIdx.x & (NXCD - 1);
    const int cb = blockIdx.x >> 3;
    const int nb = gridDim.x >> 3;
    const int lo = color * NODES_PER_COLOR;
    for (int e = cb * 256 + threadIdx.x; e < N_EDGES; e += nb * 256) {
        int d = __builtin_nontemporal_load(dst + e);
        if ((unsigned)(d - lo) < (unsigned)NODES_PER_COLOR) {
            int s = __builtin_nontemporal_load(src + e);
            int slot = atomicAdd(&dcount[d], 1);
            if (slot < MAXDEG)   // statically impossible for this graph; safety net
                csrp[((size_t)d << 6) + slot] = s;
        }
    }
}

// ------- mean aggregation (fp8 gather, padded CSR): one wave per dst node -------
// Row = 128 fp8 = 128 B = 64 lanes x 1 ushort (2 elems). f32 accumulate, bf16 out.
__global__ __launch_bounds__(256) void agg_fp8(
        const unsigned char* __restrict__ feat, const int* __restrict__ csrp,
        const int* __restrict__ dcount, unsigned short* __restrict__ out) {
    int w = (blockIdx.x * 256 + threadIdx.x) >> 6;
    int lane = threadIdx.x & 63;
    if (w >= N_NODES) return;
    int dg = __builtin_amdgcn_readfirstlane(dcount[w]);
    if (dg > MAXDEG) dg = MAXDEG;
    const int* __restrict__ row = csrp + ((size_t)w << 6);
    float ax = 0.f, ay = 0.f;
    int j = 0;
    for (; j + 8 <= dg; j += 8) {
        int s[8]; unsigned short v[8];
        #pragma unroll
        for (int u = 0; u < 8; ++u) s[u] = __builtin_nontemporal_load(row + j + u);
        #pragma unroll
        for (int u = 0; u < 8; ++u)
            v[u] = *(const unsigned short*)(feat + ((size_t)s[u] << 7) + 2 * lane);
        #pragma unroll
        for (int u = 0; u < 8; ++u) {
            floatx2 f = __builtin_amdgcn_cvt_pk_f32_fp8((unsigned)v[u], false);
            ax += f.x; ay += f.y;
        }
    }
    for (; j < dg; ++j) {
        int s = __builtin_nontemporal_load(row + j);
        unsigned short vv = *(const unsigned short*)(feat + ((size_t)s << 7) + 2 * lane);
        floatx2 f = __builtin_amdgcn_cvt_pk_f32_fp8((unsigned)vv, false);
        ax += f.x; ay += f.y;
    }
    float invd = (dg > 0) ? 1.0f / (float)dg : 1.0f;
    unsigned pv = (unsigned)f2bf(ax * invd) | ((unsigned)f2bf(ay * invd) << 16);
    *(unsigned*)(out + (size_t)w * D + 2 * lane) = pv;
}

// ---------------- pack W = [Wa;Wb] (K=256, ncols) into MFMA B-fragment order ----
__global__ void pack_w(const float* __restrict__ Wa, const float* __restrict__ Wb,
                       int ncols, unsigned short* __restrict__ out) {
    int t = blockIdx.x * blockDim.x + threadIdx.x;
    int nnt = ncols >> 4;
    int total = 8 * nnt * 64;
    if (t >= total) return;
    int lane = t & 63;
    int nt = (t >> 6) % nnt;
    int kt = t / (64 * nnt);
    int col = nt * 16 + (lane & 15);
    int k0 = kt * 32 + ((lane >> 4) << 3);
    unsigned short* dstp = out + (size_t)((kt * nnt + nt) * 64 + lane) * 8;
    #pragma unroll
    for (int j = 0; j < 8; ++j) {
        int k = k0 + j;
        float f = (k < 128) ? Wa[(size_t)k * ncols + col]
                            : Wb[(size_t)(k - 128) * ncols + col];
        dstp[j] = f2bf(f);
    }
}

// ---------------- fused SAGE dense layer: C = act([A0 | A1] @ Wp + bias) ------
// Optionally also emits an fp8 copy of C (for the next layer's gather).
template<int NT, bool RELU, bool OUT_BF16, bool WFP8>
__global__ __launch_bounds__(256) void gemm_sage(
        const unsigned short* __restrict__ A0, const unsigned short* __restrict__ A1,
        const unsigned short* __restrict__ Wp, const float* __restrict__ bias,
        void* __restrict__ Cout, unsigned char* __restrict__ C8)
{
    const int wave = threadIdx.x >> 6;
    const int lane = threadIdx.x & 63;
    const int q = lane >> 4, m = lane & 15;
    const int NCOL = NT * 16;

    int row = blockIdx.x * 64 + wave * 16 + m;
    int rowc = (row < N_NODES) ? row : (N_NODES - 1);

    floatx4 acc[NT];
    #pragma unroll
    for (int nt = 0; nt < NT; ++nt) acc[nt] = (floatx4){0.f, 0.f, 0.f, 0.f};

    #pragma unroll
    for (int kt = 0; kt < 8; ++kt) {
        const unsigned short* __restrict__ base = (kt < 4) ? A0 : A1;
        short8 af = *(const short8*)(base + (size_t)rowc * D + (kt & 3) * 32 + q * 8);
        #pragma unroll
        for (int nt = 0; nt < NT; ++nt) {
            short8 bf = *(const short8*)(Wp + (size_t)((kt * NT + nt) * 64 + lane) * 8);
            acc[nt] = __builtin_amdgcn_mfma_f32_16x16x32_bf16(af, bf, acc[nt], 0, 0, 0);
        }
    }

    const int orow_base = blockIdx.x * 64 + wave * 16 + q * 4;
    #pragma unroll
    for (int nt = 0; nt < NT; ++nt) {
        float b = bias[nt * 16 + m];
        #pragma unroll
        for (int i = 0; i < 4; ++i) {
            int orow = orow_base + i;
            if (orow < N_NODES) {
                float v = acc[nt][i] + b;
                if (RELU) v = fmaxf(v, 0.f);
                if (OUT_BF16)
                    ((unsigned short*)Cout)[(size_t)orow * NCOL + nt * 16 + m] = f2bf(v);
                else
                    ((float*)Cout)[(size_t)orow * NCOL + nt * 16 + m] = v;
                if (WFP8) {
                    int pk = __builtin_amdgcn_cvt_pk_fp8_f32(v, v, 0, false);
                    C8[(size_t)orow * NCOL + nt * 16 + m] = (unsigned char)(pk & 0xff);
                }
            }
        }
    }
}

extern "C" void kernel_launch(void* const* d_in, const int* in_sizes, int n_in,
                              void* d_out, int out_size, void* d_ws, size_t ws_size,
                              hipStream_t stream) {
    const float* x   = (const float*)d_in[0];
    const int*   src = (const int*)d_in[1];
    const int*   dst = (const int*)d_in[2];
    const float* Ws1 = (const float*)d_in[3];
    const float* Wn1 = (const float*)d_in[4];
    const float* b1  = (const float*)d_in[5];
    const float* Ws2 = (const float*)d_in[6];
    const float* Wn2 = (const float*)d_in[7];
    const float* b2  = (const float*)d_in[8];
    float* out = (float*)d_out;

    const size_t nd = (size_t)N_NODES * D;   // 12.8M elements
    unsigned short* xb   = (unsigned short*)d_ws;      // bf16 x          (25.6 MB)
    unsigned short* h    = xb + nd;                    // bf16 hidden     (25.6 MB)
    unsigned short* aggb = h + nd;                     // bf16 aggregate  (25.6 MB)
    unsigned char*  xf8  = (unsigned char*)(aggb + nd);// fp8 x           (12.8 MB)
    unsigned char*  hf8  = xf8 + nd;                   // fp8 hidden      (12.8 MB)
    int* dcount = (int*)(hf8 + nd);                    //                 (0.4 MB)
    int* csrp   = dcount + N_NODES;                    // padded CSR      (25.6 MB)
    unsigned short* Wp1 = (unsigned short*)(csrp + (size_t)N_NODES * MAXDEG);
    unsigned short* Wp2 = Wp1 + 32768;

    hipMemsetAsync(dcount, 0, N_NODES * sizeof(int), stream);

    to_bf16_fp8<<<(int)(nd / 8 + 255) / 256, 256, 0, stream>>>(x, xb, (unsigned*)xf8, (int)(nd / 8));
    pack_w<<<16, 256, 0, stream>>>(Ws1, Wn1, D, Wp1);
    pack_w<<<8, 256, 0, stream>>>(Ws2, Wn2, D_OUT, Wp2);

    build_padded<<<4096, 256, 0, stream>>>(src, dst, dcount, csrp);

    const int agg_blocks = (N_NODES * 64 + 255) / 256;   // 25000
    const int gemm_blocks = (N_NODES + 63) / 64;         // 1563

    agg_fp8<<<agg_blocks, 256, 0, stream>>>(xf8, csrp, dcount, aggb);
    gemm_sage<8, true, true, true><<<gemm_blocks, 256, 0, stream>>>(xb, aggb, Wp1, b1, h, hf8);
    agg_fp8<<<agg_blocks, 256, 0, stream>>>(hf8, csrp, dcount, aggb);
    gemm_sage<4, false, false, false><<<gemm_blocks, 256, 0, stream>>>(h, aggb, Wp2, b2, out, nullptr);
}

// Round 8
// 362.667 us; speedup vs baseline: 1.1392x; 1.1392x over previous
//
#include <hip/hip_runtime.h>

#define N_NODES 100000
#define N_EDGES 1600000
#define D 128      // D_IN == D_HID
#define D_OUT 64
#define MAXDEG 64  // Poisson(16); max over 100k nodes ~35. 64 = safe pow2.

#define NBUCK 196          // buckets of 512 nodes: ceil(100000/512)
#define BCAP  12288        // bucket capacity (avg 8192, ~50 sigma slack)
#define CHUNK 6400         // edges per phase-A block; 250*6400 = 1.6M exact
#define NBLK_A (N_EDGES / CHUNK)

typedef __attribute__((ext_vector_type(8))) short short8;   // 8 bf16 (4 VGPRs)
typedef __attribute__((ext_vector_type(4))) float floatx4;  // MFMA C/D

__device__ inline unsigned short f2bf(float f) {   // RNE f32 -> bf16
    unsigned u = __builtin_bit_cast(unsigned, f);
    u = (u + 0x7fffu + ((u >> 16) & 1u)) >> 16;
    return (unsigned short)u;
}
__device__ inline float bflo(unsigned v) { return __builtin_bit_cast(float, v << 16); }
__device__ inline float bfhi(unsigned v) { return __builtin_bit_cast(float, v & 0xffff0000u); }

// ---------------- f32 -> bf16 bulk convert (8 elems/thread) ----------------
__global__ void to_bf16(const float* __restrict__ in, unsigned short* __restrict__ out, int n8) {
    int i = blockIdx.x * blockDim.x + threadIdx.x;
    if (i >= n8) return;
    const float4* p = (const float4*)in + 2 * (size_t)i;
    float4 a = p[0], b = p[1];
    uint4 u;
    u.x = (unsigned)f2bf(a.x) | ((unsigned)f2bf(a.y) << 16);
    u.y = (unsigned)f2bf(a.z) | ((unsigned)f2bf(a.w) << 16);
    u.z = (unsigned)f2bf(b.x) | ((unsigned)f2bf(b.y) << 16);
    u.w = (unsigned)f2bf(b.z) | ((unsigned)f2bf(b.w) << 16);
    ((uint4*)out)[i] = u;
}

// ------- phase A: LDS-staged multisplit of edges into 196 dst-buckets -------
// Dense run-writes into bucket regions => write amplification ~1.
__global__ __launch_bounds__(256) void bucket_split(
        const int* __restrict__ src, const int* __restrict__ dst,
        int* __restrict__ gcur, int* __restrict__ bucketbuf) {
    __shared__ int cnt[NBUCK];
    __shared__ int base_s[NBUCK];
    const int tid = threadIdx.x;
    for (int i = tid; i < NBUCK; i += 256) cnt[i] = 0;
    __syncthreads();
    const int e0 = blockIdx.x * CHUNK;
    for (int i = tid; i < CHUNK; i += 256) {
        int d = __builtin_nontemporal_load(dst + e0 + i);
        atomicAdd(&cnt[d >> 9], 1);
    }
    __syncthreads();
    for (int i = tid; i < NBUCK; i += 256) {
        int c = cnt[i];
        base_s[i] = c ? atomicAdd(&gcur[i], c) : 0;
        cnt[i] = 0;   // reuse as per-block write cursor
    }
    __syncthreads();
    for (int i = tid; i < CHUNK; i += 256) {
        int d = __builtin_nontemporal_load(dst + e0 + i);
        int s = __builtin_nontemporal_load(src + e0 + i);
        int b = d >> 9;
        int p = base_s[b] + atomicAdd(&cnt[b], 1);
        if (p < BCAP)   // statically impossible overflow; safety net
            bucketbuf[b * BCAP + p] = ((d & 511) << 17) | s;
    }
}

// ------- phase B: per-bucket CSR build via LDS counters (no global atomics) -------
// Each block owns a 128 KB csrp window; sectors fill fully while L2-resident.
__global__ __launch_bounds__(256) void bucket_csr(
        const int* __restrict__ gcur, const int* __restrict__ bucketbuf,
        int* __restrict__ dcount, int* __restrict__ csrp) {
    __shared__ int lcnt[512];
    const int tid = threadIdx.x, b = blockIdx.x;
    for (int i = tid; i < 512; i += 256) lcnt[i] = 0;
    __syncthreads();
    int m = gcur[b]; if (m > BCAP) m = BCAP;
    const int* __restrict__ buf = bucketbuf + b * BCAP;
    for (int i = tid; i < m; i += 256) {
        int v = buf[i];
        int dloc = v >> 17, s = v & 0x1FFFF;
        int slot = atomicAdd(&lcnt[dloc], 1);
        if (slot < MAXDEG)
            csrp[(((size_t)(b << 9) + dloc) << 6) + slot] = s;
    }
    __syncthreads();
    for (int i = tid; i < 512; i += 256) {
        int node = (b << 9) + i;
        if (node < N_NODES) {
            int c = lcnt[i];
            dcount[node] = (c > MAXDEG) ? MAXDEG : c;
        }
    }
}

// ------- mean aggregation (bf16 rows, padded CSR): one wave per dst node -------
// Row = 128 bf16 = 256 B = 64 lanes x 1 dword. f32 accumulate, bf16 out.
__global__ __launch_bounds__(256) void agg_bf16(
        const unsigned short* __restrict__ feat, const int* __restrict__ csrp,
        const int* __restrict__ dcount, unsigned short* __restrict__ out) {
    int w = (blockIdx.x * 256 + threadIdx.x) >> 6;
    int lane = threadIdx.x & 63;
    if (w >= N_NODES) return;
    int dg = __builtin_amdgcn_readfirstlane(dcount[w]);
    if (dg > MAXDEG) dg = MAXDEG;
    const int* __restrict__ row = csrp + ((size_t)w << 6);
    float ax = 0.f, ay = 0.f;
    int j = 0;
    for (; j + 8 <= dg; j += 8) {
        int s[8]; unsigned v[8];
        #pragma unroll
        for (int u = 0; u < 8; ++u) s[u] = row[j + u];
        #pragma unroll
        for (int u = 0; u < 8; ++u)
            v[u] = *(const unsigned*)(feat + (size_t)s[u] * D + 2 * lane);
        #pragma unroll
        for (int u = 0; u < 8; ++u) { ax += bflo(v[u]); ay += bfhi(v[u]); }
    }
    for (; j < dg; ++j) {
        unsigned v = *(const unsigned*)(feat + (size_t)row[j] * D + 2 * lane);
        ax += bflo(v); ay += bfhi(v);
    }
    float invd = (dg > 0) ? 1.0f / (float)dg : 1.0f;
    unsigned pv = (unsigned)f2bf(ax * invd) | ((unsigned)f2bf(ay * invd) << 16);
    *(unsigned*)(out + (size_t)w * D + 2 * lane) = pv;
}

// ---------------- pack W = [Wa;Wb] (K=256, ncols) into MFMA B-fragment order ----
__global__ void pack_w(const float* __restrict__ Wa, const float* __restrict__ Wb,
                       int ncols, unsigned short* __restrict__ out) {
    int t = blockIdx.x * blockDim.x + threadIdx.x;
    int nnt = ncols >> 4;
    int total = 8 * nnt * 64;
    if (t >= total) return;
    int lane = t & 63;
    int nt = (t >> 6) % nnt;
    int kt = t / (64 * nnt);
    int col = nt * 16 + (lane & 15);
    int k0 = kt * 32 + ((lane >> 4) << 3);
    unsigned short* dstp = out + (size_t)((kt * nnt + nt) * 64 + lane) * 8;
    #pragma unroll
    for (int j = 0; j < 8; ++j) {
        int k = k0 + j;
        float f = (k < 128) ? Wa[(size_t)k * ncols + col]
                            : Wb[(size_t)(k - 128) * ncols + col];
        dstp[j] = f2bf(f);
    }
}

// ---------------- fused SAGE dense layer: C = act([A0 | A1] @ Wp + bias) ------
template<int NT, bool RELU, bool OUT_BF16>
__global__ __launch_bounds__(256) void gemm_sage(
        const unsigned short* __restrict__ A0, const unsigned short* __restrict__ A1,
        const unsigned short* __restrict__ Wp, const float* __restrict__ bias,
        void* __restrict__ Cout)
{
    const int wave = threadIdx.x >> 6;
    const int lane = threadIdx.x & 63;
    const int q = lane >> 4, m = lane & 15;
    const int NCOL = NT * 16;

    int row = blockIdx.x * 64 + wave * 16 + m;
    int rowc = (row < N_NODES) ? row : (N_NODES - 1);

    floatx4 acc[NT];
    #pragma unroll
    for (int nt = 0; nt < NT; ++nt) acc[nt] = (floatx4){0.f, 0.f, 0.f, 0.f};

    #pragma unroll
    for (int kt = 0; kt < 8; ++kt) {
        const unsigned short* __restrict__ base = (kt < 4) ? A0 : A1;
        short8 af = *(const short8*)(base + (size_t)rowc * D + (kt & 3) * 32 + q * 8);
        #pragma unroll
        for (int nt = 0; nt < NT; ++nt) {
            short8 bf = *(const short8*)(Wp + (size_t)((kt * NT + nt) * 64 + lane) * 8);
            acc[nt] = __builtin_amdgcn_mfma_f32_16x16x32_bf16(af, bf, acc[nt], 0, 0, 0);
        }
    }

    const int orow_base = blockIdx.x * 64 + wave * 16 + q * 4;
    #pragma unroll
    for (int nt = 0; nt < NT; ++nt) {
        float b = bias[nt * 16 + m];
        #pragma unroll
        for (int i = 0; i < 4; ++i) {
            int orow = orow_base + i;
            if (orow < N_NODES) {
                float v = acc[nt][i] + b;
                if (RELU) v = fmaxf(v, 0.f);
                if (OUT_BF16)
                    ((unsigned short*)Cout)[(size_t)orow * NCOL + nt * 16 + m] = f2bf(v);
                else
                    ((float*)Cout)[(size_t)orow * NCOL + nt * 16 + m] = v;
            }
        }
    }
}

extern "C" void kernel_launch(void* const* d_in, const int* in_sizes, int n_in,
                              void* d_out, int out_size, void* d_ws, size_t ws_size,
                              hipStream_t stream) {
    const float* x   = (const float*)d_in[0];
    const int*   src = (const int*)d_in[1];
    const int*   dst = (const int*)d_in[2];
    const float* Ws1 = (const float*)d_in[3];
    const float* Wn1 = (const float*)d_in[4];
    const float* b1  = (const float*)d_in[5];
    const float* Ws2 = (const float*)d_in[6];
    const float* Wn2 = (const float*)d_in[7];
    const float* b2  = (const float*)d_in[8];
    float* out = (float*)d_out;

    const size_t nd = (size_t)N_NODES * D;   // 12.8M elements
    unsigned short* xb   = (unsigned short*)d_ws;   // bf16 x           (25.6 MB)
    unsigned short* h    = xb + nd;                 // bf16 hidden      (25.6 MB)
    unsigned short* aggb = h + nd;                  // bf16 aggregate   (25.6 MB)
    int* dcount = (int*)(aggb + nd);                //                  (0.4 MB)
    int* csrp   = dcount + N_NODES;                 // padded CSR       (25.6 MB)
    int* gcur   = csrp + (size_t)N_NODES * MAXDEG;  // bucket cursors   (784 B)
    int* bucketbuf = gcur + NBUCK;                  // bucket edges     (9.6 MB)
    unsigned short* Wp1 = (unsigned short*)(bucketbuf + (size_t)NBUCK * BCAP);
    unsigned short* Wp2 = Wp1 + 32768;

    hipMemsetAsync(gcur, 0, NBUCK * sizeof(int), stream);

    to_bf16<<<(int)(nd / 8 + 255) / 256, 256, 0, stream>>>(x, xb, (int)(nd / 8));
    pack_w<<<16, 256, 0, stream>>>(Ws1, Wn1, D, Wp1);
    pack_w<<<8, 256, 0, stream>>>(Ws2, Wn2, D_OUT, Wp2);

    bucket_split<<<NBLK_A, 256, 0, stream>>>(src, dst, gcur, bucketbuf);
    bucket_csr<<<NBUCK, 256, 0, stream>>>(gcur, bucketbuf, dcount, csrp);

    const int agg_blocks = (N_NODES * 64 + 255) / 256;   // 25000
    const int gemm_blocks = (N_NODES + 63) / 64;         // 1563

    agg_bf16<<<agg_blocks, 256, 0, stream>>>(xb, csrp, dcount, aggb);
    gemm_sage<8, true, true><<<gemm_blocks, 256, 0, stream>>>(xb, aggb, Wp1, b1, h);
    agg_bf16<<<agg_blocks, 256, 0, stream>>>(h, csrp, dcount, aggb);
    gemm_sage<4, false, false><<<gemm_blocks, 256, 0, stream>>>(h, aggb, Wp2, b2, out);
}

// Round 9
// 347.166 us; speedup vs baseline: 1.1901x; 1.0446x over previous
//
#include <hip/hip_runtime.h>

#define N_NODES 100000
#define N_EDGES 1600000
#define D 128      // D_IN == D_HID
#define D_OUT 64
#define MAXDEG 64  // Poisson(16); max over 100k nodes ~35. 64 = safe pow2.

#define NBUCK 196          // buckets of 512 nodes: ceil(100000/512)
#define BCAP  12288        // bucket capacity (avg 8192, ~50 sigma slack)
#define CHUNK 6400         // edges per split block; 250*6400 = 1.6M exact
#define NBLK_A (N_EDGES / CHUNK)            // 250
#define NBLK_CVT 6250                        // 1.6M uint4-groups / 256
#define NBLK_PACK 24                         // 16 (Wp1) + 8 (Wp2)

typedef __attribute__((ext_vector_type(8))) short short8;   // 8 bf16 (4 VGPRs)
typedef __attribute__((ext_vector_type(4))) float floatx4;  // MFMA C/D
typedef __attribute__((ext_vector_type(2))) float floatx2;

__device__ inline unsigned short f2bf(float f) {   // RNE f32 -> bf16
    unsigned u = __builtin_bit_cast(unsigned, f);
    u = (u + 0x7fffu + ((u >> 16) & 1u)) >> 16;
    return (unsigned short)u;
}

// ---- pack W = [Wa;Wb] (K=256, ncols) into MFMA B-frag order (device helper) ----
__device__ inline void pack_dev(const float* __restrict__ Wa, const float* __restrict__ Wb,
                                int ncols, unsigned short* __restrict__ out, int t) {
    int nnt = ncols >> 4;
    int lane = t & 63;
    int nt = (t >> 6) % nnt;
    int kt = t / (64 * nnt);
    int col = nt * 16 + (lane & 15);
    int k0 = kt * 32 + ((lane >> 4) << 3);
    unsigned short* dstp = out + (size_t)((kt * nnt + nt) * 64 + lane) * 8;
    #pragma unroll
    for (int j = 0; j < 8; ++j) {
        int k = k0 + j;
        float f = (k < 128) ? Wa[(size_t)k * ncols + col]
                            : Wb[(size_t)(k - 128) * ncols + col];
        dstp[j] = f2bf(f);
    }
}

// ------- fused prep: bucket_split ∪ (f32->bf16+fp8 convert) ∪ weight pack -------
// All three are independent; grid-partitioned to cut dispatch count and overlap
// the 250-block split with the 6250-block convert.
__global__ __launch_bounds__(256) void prep(
        const float* __restrict__ x, const int* __restrict__ src, const int* __restrict__ dst,
        const float* __restrict__ Ws1, const float* __restrict__ Wn1,
        const float* __restrict__ Ws2, const float* __restrict__ Wn2,
        unsigned short* __restrict__ xb, unsigned* __restrict__ xf8,
        int* __restrict__ gcur, int* __restrict__ bucketbuf,
        unsigned short* __restrict__ Wp1, unsigned short* __restrict__ Wp2) {
    __shared__ int cnt[NBUCK];
    __shared__ int base_s[NBUCK];
    const int tid = threadIdx.x;
    const int b = blockIdx.x;

    if (b < NBLK_A) {
        // ---- phase A multisplit: dense run-writes, write amplification ~1 ----
        for (int i = tid; i < NBUCK; i += 256) cnt[i] = 0;
        __syncthreads();
        const int e0 = b * CHUNK;
        for (int i = tid; i < CHUNK; i += 256) {
            int d = __builtin_nontemporal_load(dst + e0 + i);
            atomicAdd(&cnt[d >> 9], 1);
        }
        __syncthreads();
        for (int i = tid; i < NBUCK; i += 256) {
            int c = cnt[i];
            base_s[i] = c ? atomicAdd(&gcur[i], c) : 0;
            cnt[i] = 0;   // reuse as per-block write cursor
        }
        __syncthreads();
        for (int i = tid; i < CHUNK; i += 256) {
            int d = __builtin_nontemporal_load(dst + e0 + i);
            int s = __builtin_nontemporal_load(src + e0 + i);
            int bk = d >> 9;
            int p = base_s[bk] + atomicAdd(&cnt[bk], 1);
            if (p < BCAP)   // statically impossible overflow; safety net
                bucketbuf[bk * BCAP + p] = ((d & 511) << 17) | s;
        }
    } else if (b < NBLK_A + NBLK_CVT) {
        // ---- f32 -> bf16 + fp8 (8 elems/thread) ----
        int i = (b - NBLK_A) * 256 + tid;   // < 1.6M exactly
        const float4* p = (const float4*)x + 2 * (size_t)i;
        float4 a = p[0], c = p[1];
        uint4 u;
        u.x = (unsigned)f2bf(a.x) | ((unsigned)f2bf(a.y) << 16);
        u.y = (unsigned)f2bf(a.z) | ((unsigned)f2bf(a.w) << 16);
        u.z = (unsigned)f2bf(c.x) | ((unsigned)f2bf(c.y) << 16);
        u.w = (unsigned)f2bf(c.z) | ((unsigned)f2bf(c.w) << 16);
        ((uint4*)xb)[i] = u;
        int v0 = __builtin_amdgcn_cvt_pk_fp8_f32(a.x, a.y, 0, false);
        v0     = __builtin_amdgcn_cvt_pk_fp8_f32(a.z, a.w, v0, true);
        int v1 = __builtin_amdgcn_cvt_pk_fp8_f32(c.x, c.y, 0, false);
        v1     = __builtin_amdgcn_cvt_pk_fp8_f32(c.z, c.w, v1, true);
        uint2 w8; w8.x = (unsigned)v0; w8.y = (unsigned)v1;
        ((uint2*)xf8)[i] = w8;
    } else {
        // ---- weight pack ----
        int sub = b - (NBLK_A + NBLK_CVT);
        if (sub < 16) pack_dev(Ws1, Wn1, D, Wp1, sub * 256 + tid);
        else          pack_dev(Ws2, Wn2, D_OUT, Wp2, (sub - 16) * 256 + tid);
    }
}

// ------- phase B: per-bucket CSR build via LDS counters (no global atomics) -------
__global__ __launch_bounds__(256) void bucket_csr(
        const int* __restrict__ gcur, const int* __restrict__ bucketbuf,
        int* __restrict__ dcount, int* __restrict__ csrp) {
    __shared__ int lcnt[512];
    const int tid = threadIdx.x, b = blockIdx.x;
    for (int i = tid; i < 512; i += 256) lcnt[i] = 0;
    __syncthreads();
    int m = gcur[b]; if (m > BCAP) m = BCAP;
    const int* __restrict__ buf = bucketbuf + b * BCAP;
    for (int i = tid; i < m; i += 256) {
        int v = buf[i];
        int dloc = v >> 17, s = v & 0x1FFFF;
        int slot = atomicAdd(&lcnt[dloc], 1);
        if (slot < MAXDEG)
            csrp[(((size_t)(b << 9) + dloc) << 6) + slot] = s;
    }
    __syncthreads();
    for (int i = tid; i < 512; i += 256) {
        int node = (b << 9) + i;
        if (node < N_NODES) {
            int c = lcnt[i];
            dcount[node] = (c > MAXDEG) ? MAXDEG : c;
        }
    }
}

// ------- mean aggregation (fp8 gather): one wave per node, 2 edges per load -------
// Lane = (parity=lane>>5, colquad=lane&31): uint load covers 4 fp8 cols of one
// edge row; lanes 0-31 handle even edges, 32-63 odd. Shuffle-combine, bf16 out.
// NO nontemporal anywhere (r7 lesson: NT on hot csrp rows adds miss latency).
__global__ __launch_bounds__(256) void agg_fp8(
        const unsigned char* __restrict__ feat, const int* __restrict__ csrp,
        const int* __restrict__ dcount, unsigned short* __restrict__ out) {
    int w = (blockIdx.x * 256 + threadIdx.x) >> 6;
    int lane = threadIdx.x & 63;
    if (w >= N_NODES) return;
    int dg = __builtin_amdgcn_readfirstlane(dcount[w]);
    const int* __restrict__ row = csrp + ((size_t)w << 6);
    const int half = lane >> 5;
    const int c4 = (lane & 31) << 2;   // column base (x4 fp8)
    float a0 = 0.f, a1 = 0.f, a2 = 0.f, a3 = 0.f;
    int j = 0;
    for (; j + 16 <= dg; j += 16) {
        int s[8]; unsigned v[8];
        #pragma unroll
        for (int u = 0; u < 8; ++u) s[u] = row[j + 2 * u + half];
        #pragma unroll
        for (int u = 0; u < 8; ++u)
            v[u] = *(const unsigned*)(feat + ((size_t)s[u] << 7) + c4);
        #pragma unroll
        for (int u = 0; u < 8; ++u) {
            floatx2 lo = __builtin_amdgcn_cvt_pk_f32_fp8(v[u], false);
            floatx2 hi = __builtin_amdgcn_cvt_pk_f32_fp8(v[u], true);
            a0 += lo.x; a1 += lo.y; a2 += hi.x; a3 += hi.y;
        }
    }
    for (; j + 2 <= dg; j += 2) {
        int s = row[j + half];
        unsigned v = *(const unsigned*)(feat + ((size_t)s << 7) + c4);
        floatx2 lo = __builtin_amdgcn_cvt_pk_f32_fp8(v, false);
        floatx2 hi = __builtin_amdgcn_cvt_pk_f32_fp8(v, true);
        a0 += lo.x; a1 += lo.y; a2 += hi.x; a3 += hi.y;
    }
    if (j < dg && half == 0) {   // odd tail: even-parity lanes only
        int s = row[j];
        unsigned v = *(const unsigned*)(feat + ((size_t)s << 7) + c4);
        floatx2 lo = __builtin_amdgcn_cvt_pk_f32_fp8(v, false);
        floatx2 hi = __builtin_amdgcn_cvt_pk_f32_fp8(v, true);
        a0 += lo.x; a1 += lo.y; a2 += hi.x; a3 += hi.y;
    }
    // fold odd-parity partial sums into lanes 0-31
    a0 += __shfl_down(a0, 32); a1 += __shfl_down(a1, 32);
    a2 += __shfl_down(a2, 32); a3 += __shfl_down(a3, 32);
    if (half == 0) {
        float invd = (dg > 0) ? 1.0f / (float)dg : 1.0f;
        uint2 pv;
        pv.x = (unsigned)f2bf(a0 * invd) | ((unsigned)f2bf(a1 * invd) << 16);
        pv.y = (unsigned)f2bf(a2 * invd) | ((unsigned)f2bf(a3 * invd) << 16);
        *(uint2*)(out + (size_t)w * D + c4) = pv;   // 32 lanes x 8 B = full row
    }
}

// ---------------- fused SAGE dense layer: C = act([A0 | A1] @ Wp + bias) ------
// Optionally also emits an fp8 copy of C (for the next layer's gather).
template<int NT, bool RELU, bool OUT_BF16, bool WFP8>
__global__ __launch_bounds__(256) void gemm_sage(
        const unsigned short* __restrict__ A0, const unsigned short* __restrict__ A1,
        const unsigned short* __restrict__ Wp, const float* __restrict__ bias,
        void* __restrict__ Cout, unsigned char* __restrict__ C8)
{
    const int wave = threadIdx.x >> 6;
    const int lane = threadIdx.x & 63;
    const int q = lane >> 4, m = lane & 15;
    const int NCOL = NT * 16;

    int row = blockIdx.x * 64 + wave * 16 + m;
    int rowc = (row < N_NODES) ? row : (N_NODES - 1);

    floatx4 acc[NT];
    #pragma unroll
    for (int nt = 0; nt < NT; ++nt) acc[nt] = (floatx4){0.f, 0.f, 0.f, 0.f};

    #pragma unroll
    for (int kt = 0; kt < 8; ++kt) {
        const unsigned short* __restrict__ base = (kt < 4) ? A0 : A1;
        short8 af = *(const short8*)(base + (size_t)rowc * D + (kt & 3) * 32 + q * 8);
        #pragma unroll
        for (int nt = 0; nt < NT; ++nt) {
            short8 bf = *(const short8*)(Wp + (size_t)((kt * NT + nt) * 64 + lane) * 8);
            acc[nt] = __builtin_amdgcn_mfma_f32_16x16x32_bf16(af, bf, acc[nt], 0, 0, 0);
        }
    }

    const int orow_base = blockIdx.x * 64 + wave * 16 + q * 4;
    #pragma unroll
    for (int nt = 0; nt < NT; ++nt) {
        float b = bias[nt * 16 + m];
        #pragma unroll
        for (int i = 0; i < 4; ++i) {
            int orow = orow_base + i;
            if (orow < N_NODES) {
                float v = acc[nt][i] + b;
                if (RELU) v = fmaxf(v, 0.f);
                if (OUT_BF16)
                    ((unsigned short*)Cout)[(size_t)orow * NCOL + nt * 16 + m] = f2bf(v);
                else
                    ((float*)Cout)[(size_t)orow * NCOL + nt * 16 + m] = v;
                if (WFP8) {
                    int pk = __builtin_amdgcn_cvt_pk_fp8_f32(v, v, 0, false);
                    C8[(size_t)orow * NCOL + nt * 16 + m] = (unsigned char)(pk & 0xff);
                }
            }
        }
    }
}

extern "C" void kernel_launch(void* const* d_in, const int* in_sizes, int n_in,
                              void* d_out, int out_size, void* d_ws, size_t ws_size,
                              hipStream_t stream) {
    const float* x   = (const float*)d_in[0];
    const int*   src = (const int*)d_in[1];
    const int*   dst = (const int*)d_in[2];
    const float* Ws1 = (const float*)d_in[3];
    const float* Wn1 = (const float*)d_in[4];
    const float* b1  = (const float*)d_in[5];
    const float* Ws2 = (const float*)d_in[6];
    const float* Wn2 = (const float*)d_in[7];
    const float* b2  = (const float*)d_in[8];
    float* out = (float*)d_out;

    const size_t nd = (size_t)N_NODES * D;   // 12.8M elements
    unsigned short* xb   = (unsigned short*)d_ws;      // bf16 x          (25.6 MB)
    unsigned short* h    = xb + nd;                    // bf16 hidden     (25.6 MB)
    unsigned short* aggb = h + nd;                     // bf16 aggregate  (25.6 MB)
    unsigned char*  xf8  = (unsigned char*)(aggb + nd);// fp8 x           (12.8 MB)
    unsigned char*  hf8  = xf8 + nd;                   // fp8 hidden      (12.8 MB)
    int* dcount = (int*)(hf8 + nd);                    //                 (0.4 MB)
    int* csrp   = dcount + N_NODES;                    // padded CSR      (25.6 MB)
    int* gcur   = csrp + (size_t)N_NODES * MAXDEG;     // bucket cursors
    int* bucketbuf = gcur + 256;                       // bucket edges    (9.6 MB)
    unsigned short* Wp1 = (unsigned short*)(bucketbuf + (size_t)NBUCK * BCAP);
    unsigned short* Wp2 = Wp1 + 32768;

    hipMemsetAsync(gcur, 0, NBUCK * sizeof(int), stream);

    prep<<<NBLK_A + NBLK_CVT + NBLK_PACK, 256, 0, stream>>>(
        x, src, dst, Ws1, Wn1, Ws2, Wn2, xb, (unsigned*)xf8, gcur, bucketbuf, Wp1, Wp2);
    bucket_csr<<<NBUCK, 256, 0, stream>>>(gcur, bucketbuf, dcount, csrp);

    const int agg_blocks = (N_NODES * 64 + 255) / 256;   // 25000
    const int gemm_blocks = (N_NODES + 63) / 64;         // 1563

    agg_fp8<<<agg_blocks, 256, 0, stream>>>(xf8, csrp, dcount, aggb);
    gemm_sage<8, true, true, true><<<gemm_blocks, 256, 0, stream>>>(xb, aggb, Wp1, b1, h, hf8);
    agg_fp8<<<agg_blocks, 256, 0, stream>>>(hf8, csrp, dcount, aggb);
    gemm_sage<4, false, false, false><<<gemm_blocks, 256, 0, stream>>>(h, aggb, Wp2, b2, out, nullptr);
}

// Round 10
// 306.127 us; speedup vs baseline: 1.3496x; 1.1341x over previous
//
#include <hip/hip_runtime.h>

#define N_NODES 100000
#define N_EDGES 1600000
#define D 128      // D_IN == D_HID
#define D_OUT 64
#define MAXDEG 64  // Poisson(16); max over 100k nodes ~35. 64 = safe pow2.

#define NBUCK 196          // buckets of 512 nodes: ceil(100000/512)
#define BCAP  12288        // bucket capacity (avg 8192, ~50 sigma slack)
#define CHUNK 6400         // edges per split block; 250*6400 = 1.6M exact
#define NBLK_A (N_EDGES / CHUNK)            // 250
#define NBLK_CVT 6250                        // 1.6M uint4-groups / 256
#define NBLK_PACK 24                         // 16 (Wp1) + 8 (Wp2)

typedef __attribute__((ext_vector_type(8))) short short8;   // 8 bf16 (4 VGPRs)
typedef __attribute__((ext_vector_type(4))) float floatx4;  // MFMA C/D
typedef __attribute__((ext_vector_type(2))) float floatx2;

__device__ inline unsigned short f2bf(float f) {   // RNE f32 -> bf16
    unsigned u = __builtin_bit_cast(unsigned, f);
    u = (u + 0x7fffu + ((u >> 16) & 1u)) >> 16;
    return (unsigned short)u;
}

// ---- pack W = [Wa;Wb] (K=256, ncols) into MFMA B-frag order (device helper) ----
__device__ inline void pack_dev(const float* __restrict__ Wa, const float* __restrict__ Wb,
                                int ncols, unsigned short* __restrict__ out, int t) {
    int nnt = ncols >> 4;
    int lane = t & 63;
    int nt = (t >> 6) % nnt;
    int kt = t / (64 * nnt);
    int col = nt * 16 + (lane & 15);
    int k0 = kt * 32 + ((lane >> 4) << 3);
    unsigned short* dstp = out + (size_t)((kt * nnt + nt) * 64 + lane) * 8;
    #pragma unroll
    for (int j = 0; j < 8; ++j) {
        int k = k0 + j;
        float f = (k < 128) ? Wa[(size_t)k * ncols + col]
                            : Wb[(size_t)(k - 128) * ncols + col];
        dstp[j] = f2bf(f);
    }
}

// ------- fused prep: bucket_split ∪ (f32->bf16+fp8 convert) ∪ weight pack -------
__global__ __launch_bounds__(256) void prep(
        const float* __restrict__ x, const int* __restrict__ src, const int* __restrict__ dst,
        const float* __restrict__ Ws1, const float* __restrict__ Wn1,
        const float* __restrict__ Ws2, const float* __restrict__ Wn2,
        unsigned short* __restrict__ xb, unsigned* __restrict__ xf8,
        int* __restrict__ gcur, int* __restrict__ bucketbuf,
        unsigned short* __restrict__ Wp1, unsigned short* __restrict__ Wp2) {
    __shared__ int cnt[NBUCK];
    __shared__ int base_s[NBUCK];
    const int tid = threadIdx.x;
    const int b = blockIdx.x;

    if (b < NBLK_A) {
        // ---- phase A multisplit: dense run-writes, write amplification ~1 ----
        for (int i = tid; i < NBUCK; i += 256) cnt[i] = 0;
        __syncthreads();
        const int e0 = b * CHUNK;
        for (int i = tid; i < CHUNK; i += 256) {
            int d = __builtin_nontemporal_load(dst + e0 + i);
            atomicAdd(&cnt[d >> 9], 1);
        }
        __syncthreads();
        for (int i = tid; i < NBUCK; i += 256) {
            int c = cnt[i];
            base_s[i] = c ? atomicAdd(&gcur[i], c) : 0;
            cnt[i] = 0;   // reuse as per-block write cursor
        }
        __syncthreads();
        for (int i = tid; i < CHUNK; i += 256) {
            int d = __builtin_nontemporal_load(dst + e0 + i);
            int s = __builtin_nontemporal_load(src + e0 + i);
            int bk = d >> 9;
            int p = base_s[bk] + atomicAdd(&cnt[bk], 1);
            if (p < BCAP)   // statically impossible overflow; safety net
                bucketbuf[bk * BCAP + p] = ((d & 511) << 17) | s;
        }
    } else if (b < NBLK_A + NBLK_CVT) {
        // ---- f32 -> bf16 + fp8 (8 elems/thread) ----
        int i = (b - NBLK_A) * 256 + tid;   // < 1.6M exactly
        const float4* p = (const float4*)x + 2 * (size_t)i;
        float4 a = p[0], c = p[1];
        uint4 u;
        u.x = (unsigned)f2bf(a.x) | ((unsigned)f2bf(a.y) << 16);
        u.y = (unsigned)f2bf(a.z) | ((unsigned)f2bf(a.w) << 16);
        u.z = (unsigned)f2bf(c.x) | ((unsigned)f2bf(c.y) << 16);
        u.w = (unsigned)f2bf(c.z) | ((unsigned)f2bf(c.w) << 16);
        ((uint4*)xb)[i] = u;
        int v0 = __builtin_amdgcn_cvt_pk_fp8_f32(a.x, a.y, 0, false);
        v0     = __builtin_amdgcn_cvt_pk_fp8_f32(a.z, a.w, v0, true);
        int v1 = __builtin_amdgcn_cvt_pk_fp8_f32(c.x, c.y, 0, false);
        v1     = __builtin_amdgcn_cvt_pk_fp8_f32(c.z, c.w, v1, true);
        uint2 w8; w8.x = (unsigned)v0; w8.y = (unsigned)v1;
        ((uint2*)xf8)[i] = w8;
    } else {
        // ---- weight pack ----
        int sub = b - (NBLK_A + NBLK_CVT);
        if (sub < 16) pack_dev(Ws1, Wn1, D, Wp1, sub * 256 + tid);
        else          pack_dev(Ws2, Wn2, D_OUT, Wp2, (sub - 16) * 256 + tid);
    }
}

// ------- phase B: per-bucket CSR build via LDS counters (no global atomics) -------
__global__ __launch_bounds__(256) void bucket_csr(
        const int* __restrict__ gcur, const int* __restrict__ bucketbuf,
        int* __restrict__ dcount, int* __restrict__ csrp) {
    __shared__ int lcnt[512];
    const int tid = threadIdx.x, b = blockIdx.x;
    for (int i = tid; i < 512; i += 256) lcnt[i] = 0;
    __syncthreads();
    int m = gcur[b]; if (m > BCAP) m = BCAP;
    const int* __restrict__ buf = bucketbuf + b * BCAP;
    for (int i = tid; i < m; i += 256) {
        int v = buf[i];
        int dloc = v >> 17, s = v & 0x1FFFF;
        int slot = atomicAdd(&lcnt[dloc], 1);
        if (slot < MAXDEG)
            csrp[(((size_t)(b << 9) + dloc) << 6) + slot] = s;
    }
    __syncthreads();
    for (int i = tid; i < 512; i += 256) {
        int node = (b << 9) + i;
        if (node < N_NODES) {
            int c = lcnt[i];
            dcount[node] = (c > MAXDEG) ? MAXDEG : c;
        }
    }
}

// ------- mean aggregation (fp8 gather): one wave per node, 2 edges per load -------
// KEY CHANGE (r10): the padded CSR row (64 ints) is loaded ONCE via row[lane];
// indices are then broadcast register-to-register with __shfl (ds_bpermute).
// No memory-dependent index stage between gathers -> all dg gathers issue
// back-to-back; tail pairs are register-fed too.
__global__ __launch_bounds__(256) void agg_fp8(
        const unsigned char* __restrict__ feat, const int* __restrict__ csrp,
        const int* __restrict__ dcount, unsigned short* __restrict__ out) {
    int w = (blockIdx.x * 256 + threadIdx.x) >> 6;
    int lane = threadIdx.x & 63;
    if (w >= N_NODES) return;
    int dg = __builtin_amdgcn_readfirstlane(dcount[w]);
    const int half = lane >> 5;
    const int c4 = (lane & 31) << 2;   // column base (x4 fp8)
    int idxv = csrp[((size_t)w << 6) + lane];   // whole padded row, one load
    float a0 = 0.f, a1 = 0.f, a2 = 0.f, a3 = 0.f;
    int j = 0;
    for (; j + 8 <= dg; j += 8) {      // 4 pairs = 8 edges in flight
        int s[4]; unsigned v[4];
        #pragma unroll
        for (int u = 0; u < 4; ++u) s[u] = __shfl(idxv, j + 2 * u + half);
        #pragma unroll
        for (int u = 0; u < 4; ++u)
            v[u] = *(const unsigned*)(feat + ((size_t)s[u] << 7) + c4);
        #pragma unroll
        for (int u = 0; u < 4; ++u) {
            floatx2 lo = __builtin_amdgcn_cvt_pk_f32_fp8(v[u], false);
            floatx2 hi = __builtin_amdgcn_cvt_pk_f32_fp8(v[u], true);
            a0 += lo.x; a1 += lo.y; a2 += hi.x; a3 += hi.y;
        }
    }
    for (; j + 2 <= dg; j += 2) {      // remaining pairs (register-fed)
        int s = __shfl(idxv, j + half);
        unsigned v = *(const unsigned*)(feat + ((size_t)s << 7) + c4);
        floatx2 lo = __builtin_amdgcn_cvt_pk_f32_fp8(v, false);
        floatx2 hi = __builtin_amdgcn_cvt_pk_f32_fp8(v, true);
        a0 += lo.x; a1 += lo.y; a2 += hi.x; a3 += hi.y;
    }
    if (j < dg) {                      // odd tail: uniform shuffle, half==0 loads
        int s = __shfl(idxv, j);
        if (half == 0) {
            unsigned v = *(const unsigned*)(feat + ((size_t)s << 7) + c4);
            floatx2 lo = __builtin_amdgcn_cvt_pk_f32_fp8(v, false);
            floatx2 hi = __builtin_amdgcn_cvt_pk_f32_fp8(v, true);
            a0 += lo.x; a1 += lo.y; a2 += hi.x; a3 += hi.y;
        }
    }
    // fold odd-parity partial sums into lanes 0-31
    a0 += __shfl_down(a0, 32); a1 += __shfl_down(a1, 32);
    a2 += __shfl_down(a2, 32); a3 += __shfl_down(a3, 32);
    if (half == 0) {
        float invd = (dg > 0) ? 1.0f / (float)dg : 1.0f;
        uint2 pv;
        pv.x = (unsigned)f2bf(a0 * invd) | ((unsigned)f2bf(a1 * invd) << 16);
        pv.y = (unsigned)f2bf(a2 * invd) | ((unsigned)f2bf(a3 * invd) << 16);
        *(uint2*)(out + (size_t)w * D + c4) = pv;   // 32 lanes x 8 B = full row
    }
}

// ---------------- fused SAGE dense layer: C = act([A0 | A1] @ Wp + bias) ------
// Optionally also emits an fp8 copy of C (for the next layer's gather).
template<int NT, bool RELU, bool OUT_BF16, bool WFP8>
__global__ __launch_bounds__(256) void gemm_sage(
        const unsigned short* __restrict__ A0, const unsigned short* __restrict__ A1,
        const unsigned short* __restrict__ Wp, const float* __restrict__ bias,
        void* __restrict__ Cout, unsigned char* __restrict__ C8)
{
    const int wave = threadIdx.x >> 6;
    const int lane = threadIdx.x & 63;
    const int q = lane >> 4, m = lane & 15;
    const int NCOL = NT * 16;

    int row = blockIdx.x * 64 + wave * 16 + m;
    int rowc = (row < N_NODES) ? row : (N_NODES - 1);

    floatx4 acc[NT];
    #pragma unroll
    for (int nt = 0; nt < NT; ++nt) acc[nt] = (floatx4){0.f, 0.f, 0.f, 0.f};

    #pragma unroll
    for (int kt = 0; kt < 8; ++kt) {
        const unsigned short* __restrict__ base = (kt < 4) ? A0 : A1;
        short8 af = *(const short8*)(base + (size_t)rowc * D + (kt & 3) * 32 + q * 8);
        #pragma unroll
        for (int nt = 0; nt < NT; ++nt) {
            short8 bf = *(const short8*)(Wp + (size_t)((kt * NT + nt) * 64 + lane) * 8);
            acc[nt] = __builtin_amdgcn_mfma_f32_16x16x32_bf16(af, bf, acc[nt], 0, 0, 0);
        }
    }

    const int orow_base = blockIdx.x * 64 + wave * 16 + q * 4;
    #pragma unroll
    for (int nt = 0; nt < NT; ++nt) {
        float b = bias[nt * 16 + m];
        #pragma unroll
        for (int i = 0; i < 4; ++i) {
            int orow = orow_base + i;
            if (orow < N_NODES) {
                float v = acc[nt][i] + b;
                if (RELU) v = fmaxf(v, 0.f);
                if (OUT_BF16)
                    ((unsigned short*)Cout)[(size_t)orow * NCOL + nt * 16 + m] = f2bf(v);
                else
                    ((float*)Cout)[(size_t)orow * NCOL + nt * 16 + m] = v;
                if (WFP8) {
                    int pk = __builtin_amdgcn_cvt_pk_fp8_f32(v, v, 0, false);
                    C8[(size_t)orow * NCOL + nt * 16 + m] = (unsigned char)(pk & 0xff);
                }
            }
        }
    }
}

extern "C" void kernel_launch(void* const* d_in, const int* in_sizes, int n_in,
                              void* d_out, int out_size, void* d_ws, size_t ws_size,
                              hipStream_t stream) {
    const float* x   = (const float*)d_in[0];
    const int*   src = (const int*)d_in[1];
    const int*   dst = (const int*)d_in[2];
    const float* Ws1 = (const float*)d_in[3];
    const float* Wn1 = (const float*)d_in[4];
    const float* b1  = (const float*)d_in[5];
    const float* Ws2 = (const float*)d_in[6];
    const float* Wn2 = (const float*)d_in[7];
    const float* b2  = (const float*)d_in[8];
    float* out = (float*)d_out;

    const size_t nd = (size_t)N_NODES * D;   // 12.8M elements
    unsigned short* xb   = (unsigned short*)d_ws;      // bf16 x          (25.6 MB)
    unsigned short* h    = xb + nd;                    // bf16 hidden     (25.6 MB)
    unsigned short* aggb = h + nd;                     // bf16 aggregate  (25.6 MB)
    unsigned char*  xf8  = (unsigned char*)(aggb + nd);// fp8 x           (12.8 MB)
    unsigned char*  hf8  = xf8 + nd;                   // fp8 hidden      (12.8 MB)
    int* dcount = (int*)(hf8 + nd);                    //                 (0.4 MB)
    int* csrp   = dcount + N_NODES;                    // padded CSR      (25.6 MB)
    int* gcur   = csrp + (size_t)N_NODES * MAXDEG;     // bucket cursors
    int* bucketbuf = gcur + 256;                       // bucket edges    (9.6 MB)
    unsigned short* Wp1 = (unsigned short*)(bucketbuf + (size_t)NBUCK * BCAP);
    unsigned short* Wp2 = Wp1 + 32768;

    hipMemsetAsync(gcur, 0, NBUCK * sizeof(int), stream);

    prep<<<NBLK_A + NBLK_CVT + NBLK_PACK, 256, 0, stream>>>(
        x, src, dst, Ws1, Wn1, Ws2, Wn2, xb, (unsigned*)xf8, gcur, bucketbuf, Wp1, Wp2);
    bucket_csr<<<NBUCK, 256, 0, stream>>>(gcur, bucketbuf, dcount, csrp);

    const int agg_blocks = (N_NODES * 64 + 255) / 256;   // 25000
    const int gemm_blocks = (N_NODES + 63) / 64;         // 1563

    agg_fp8<<<agg_blocks, 256, 0, stream>>>(xf8, csrp, dcount, aggb);
    gemm_sage<8, true, true, true><<<gemm_blocks, 256, 0, stream>>>(xb, aggb, Wp1, b1, h, hf8);
    agg_fp8<<<agg_blocks, 256, 0, stream>>>(hf8, csrp, dcount, aggb);
    gemm_sage<4, false, false, false><<<gemm_blocks, 256, 0, stream>>>(h, aggb, Wp2, b2, out, nullptr);
}